// Round 6
// baseline (382.048 us; speedup 1.0000x reference)
//
#include <hip/hip_runtime.h>
#include <math.h>

#define Bz 32
#define Lz 2048
#define Hz 768
#define Tz 12
#define Ez 7
#define EMPTYIDX 6
#define NCOL 24          // T*2 logit columns per batch
#define RPB 32           // L-rows per k2 block
#define NCH 64           // Lz / RPB logsumexp partial chunks

typedef float f32x4 __attribute__((ext_vector_type(4)));
typedef short s16x8 __attribute__((ext_vector_type(8)));   // 8 bf16 (guide §3)

// ---------------- kernel 1a: cW partial dots, H split across blocks ----------
#define K1A_ZC 3
#define K1A_HB 48
#define K1A_HC 16
__global__ void k1a_cw(const float* __restrict__ seq, const float* __restrict__ W,
                       const int* __restrict__ turns, const int* __restrict__ midx,
                       float* __restrict__ cW) {
    int bx = blockIdx.x;
    int e  = bx % Ez;
    int zc = (bx / Ez) % K1A_ZC;
    int hc = bx / (Ez * K1A_ZC);           // 0..15
    int z  = zc * 256 + threadIdx.x;       // 0..767
    int h0 = hc * K1A_HB;
    int tid = threadIdx.x;

    __shared__ int itemsS[Bz * Tz];
    __shared__ int cntS;
    if (tid == 0) cntS = 0;
    __syncthreads();
    for (int i = tid; i < Bz * Tz; i += 256) {
        int ei = midx[i];
        ei = min(max(ei, 0), Ez - 1);
        if (ei == e) {
            int p = atomicAdd(&cntS, 1);
            itemsS[p] = i;
        }
    }
    __syncthreads();
    int cnt = cntS;

    const float* Wb = W + ((size_t)e * Hz + h0) * Hz + z;
    float w[K1A_HB];
#pragma unroll
    for (int j = 0; j < K1A_HB; ++j) w[j] = Wb[(size_t)j * Hz];

    for (int n = 0; n < cnt; ++n) {
        int i  = itemsS[n];                // block-uniform
        int b  = i / Tz;
        int st = turns[2 * i];
        st = min(max(st, 0), Lz - 1);
        const float* c = seq + ((size_t)(b * Lz + st)) * Hz + h0;  // uniform -> s_load
        float acc = 0.f;
#pragma unroll
        for (int j = 0; j < K1A_HB; ++j) acc = fmaf(c[j], w[j], acc);
        atomicAdd(&cW[(size_t)i * Hz + z], acc);
    }
}

// ---------------- kernel 1b: v = cW * spanw (elementwise) --------------------
__global__ void k1b_v(const float* __restrict__ cW, const float* __restrict__ spanw,
                      const int* __restrict__ midx, float* __restrict__ v) {
    int idx = blockIdx.x * 256 + threadIdx.x;   // 384*768 = 294912
    int i = idx / Hz;
    int z = idx - i * Hz;
    int e = midx[i];
    e = min(max(e, 0), Ez - 1);
    float cw = cW[idx];
    int b = i / Tz, t = i - b * Tz;
    size_t vb = ((size_t)(b * NCOL + t * 2)) * Hz + z;
    v[vb]      = cw * spanw[(e * Hz + z) * 2 + 0];
    v[vb + Hz] = cw * spanw[(e * Hz + z) * 2 + 1];
}

// ---------------- kernel 2: MFMA logits + logsumexp partials + picked --------
// grid = Bz*NCH = 2048 one-wave blocks (8 waves/CU, pure TLP latency hiding).
// Per block: 32 L-rows x 24(+8 pad) cols, K-loop 12 tiles of 64.
// Stage f32 -> bf16(RNE) into LDS: row stride 40 dw (frag b128 reads: uniform
// 8-accesses/bank = ideal; stage b64 writes: uniform 4/bank = ideal).
// mfma_f32_16x16x32_bf16, 2 m-tiles x 2 n-tiles. A/B frag: elem dim = lane&15,
// k = (lane>>4)*8 + j. C/D: col = lane&15, row = (lane>>4)*4 + reg (m89).
// picked logit extracted from the owning C-fragment lane (kills old k3).
__device__ __forceinline__ unsigned int pk2(float x, float y) {
    unsigned int a = __float_as_uint(x), b = __float_as_uint(y);
    a = a + 0x7FFFu + ((a >> 16) & 1u);    // RNE to bf16
    b = b + 0x7FFFu + ((b >> 16) & 1u);
    return (a >> 16) | (b & 0xFFFF0000u);
}

__global__ void __launch_bounds__(64, 2)
k2_mfma(const float* __restrict__ seq, const float* __restrict__ v,
        const int* __restrict__ kps,
        float* __restrict__ pm, float* __restrict__ ps,
        float* __restrict__ picked) {
    int bx   = blockIdx.x;
    int b    = bx >> 6;                    // /NCH
    int ch   = bx & (NCH - 1);
    int l0   = ch * RPB;
    int lane = threadIdx.x;
    int n16  = lane & 15, quad = lane >> 4;

    __shared__ unsigned int lds_u[2560];   // A: [0,1280) = 32 rows x 40 dw; V: [1280,2560)

    // zero V pad rows 24..31 (cols 24..31 garbage guard) — persists all tiles
    {
        int base = 1280 + 24 * 40 + lane * 5;
#pragma unroll
        for (int j = 0; j < 5; ++j) lds_u[base + j] = 0;
    }

    const float* A = seq + ((size_t)b * Lz + l0) * Hz;
    const float* V = v + (size_t)b * NCOL * Hz;

    f32x4 acc[2][2];
#pragma unroll
    for (int mt = 0; mt < 2; ++mt)
#pragma unroll
        for (int nt = 0; nt < 2; ++nt) acc[mt][nt] = (f32x4){0.f, 0.f, 0.f, 0.f};

    for (int kt = 0; kt < 12; ++kt) {
        int k0 = kt * 64;
        float4 ra[8], rv[6];
#pragma unroll
        for (int p = 0; p < 8; ++p) {      // A: 32 rows x 16 float4-chunks
            int c = p * 64 + lane, r = c >> 4, qc = c & 15;
            ra[p] = *(const float4*)&A[(size_t)r * Hz + k0 + qc * 4];
        }
#pragma unroll
        for (int p = 0; p < 6; ++p) {      // V: 24 rows x 16 chunks
            int c = p * 64 + lane, r = c >> 4, qc = c & 15;
            rv[p] = *(const float4*)&V[(size_t)r * Hz + k0 + qc * 4];
        }
        __syncthreads();                   // prior tile's frag reads done
#pragma unroll
        for (int p = 0; p < 8; ++p) {
            int c = p * 64 + lane, r = c >> 4, qc = c & 15;
            uint2 w; w.x = pk2(ra[p].x, ra[p].y); w.y = pk2(ra[p].z, ra[p].w);
            *(uint2*)&lds_u[r * 40 + qc * 2] = w;
        }
#pragma unroll
        for (int p = 0; p < 6; ++p) {
            int c = p * 64 + lane, r = c >> 4, qc = c & 15;
            uint2 w; w.x = pk2(rv[p].x, rv[p].y); w.y = pk2(rv[p].z, rv[p].w);
            *(uint2*)&lds_u[1280 + r * 40 + qc * 2] = w;
        }
        __syncthreads();                   // staged tile visible
#pragma unroll
        for (int s = 0; s < 2; ++s) {      // two k-sub-tiles of 32
            s16x8 af0 = *(const s16x8*)&lds_u[(0 * 16 + n16) * 40 + (s * 4 + quad) * 4];
            s16x8 af1 = *(const s16x8*)&lds_u[(1 * 16 + n16) * 40 + (s * 4 + quad) * 4];
            s16x8 bf0 = *(const s16x8*)&lds_u[1280 + (0 * 16 + n16) * 40 + (s * 4 + quad) * 4];
            s16x8 bf1 = *(const s16x8*)&lds_u[1280 + (1 * 16 + n16) * 40 + (s * 4 + quad) * 4];
            acc[0][0] = __builtin_amdgcn_mfma_f32_16x16x32_bf16(af0, bf0, acc[0][0], 0, 0, 0);
            acc[0][1] = __builtin_amdgcn_mfma_f32_16x16x32_bf16(af0, bf1, acc[0][1], 0, 0, 0);
            acc[1][0] = __builtin_amdgcn_mfma_f32_16x16x32_bf16(af1, bf0, acc[1][0], 0, 0, 0);
            acc[1][1] = __builtin_amdgcn_mfma_f32_16x16x32_bf16(af1, bf1, acc[1][1], 0, 0, 0);
        }
    }

    // logsumexp partials: lane holds rows {mt*16 + quad*4 + reg} for col nt*16+n16
#pragma unroll
    for (int nt = 0; nt < 2; ++nt) {
        f32x4 u0 = acc[0][nt], u1 = acc[1][nt];
        float m = fmaxf(fmaxf(fmaxf(u0.x, u0.y), fmaxf(u0.z, u0.w)),
                        fmaxf(fmaxf(u1.x, u1.y), fmaxf(u1.z, u1.w)));
        float s = expf(u0.x - m) + expf(u0.y - m) + expf(u0.z - m) + expf(u0.w - m)
                + expf(u1.x - m) + expf(u1.y - m) + expf(u1.z - m) + expf(u1.w - m);
        // combine across the 4 quads (lanes differing in bits 4-5)
#pragma unroll
        for (int mask = 16; mask <= 32; mask += 16) {
            float om = __shfl_xor(m, mask, 64);
            float os = __shfl_xor(s, mask, 64);
            float nm = fmaxf(m, om);
            s = s * expf(m - nm) + os * expf(om - nm);
            m = nm;
        }
        int c = nt * 16 + n16;
        if (quad == 0 && c < NCOL) {
            pm[((size_t)b * NCOL + c) * NCH + ch] = m;
            ps[((size_t)b * NCOL + c) * NCH + ch] = s;
        }
    }

    // picked logits: owner lane writes the C-fragment element at the target row
#pragma unroll
    for (int c = 0; c < NCOL; ++c) {
        int t = c >> 1, kk = c & 1;
        int tgt = kps[(b * Tz + t) * 2 + kk];
        int safe = min(max(tgt, 0), Lz - 1);
        if ((safe >> 5) == ch) {
            int lr = safe & 31;
            int nt = c >> 4, n16c = c & 15;
            int mt = lr >> 4, qo = (lr >> 2) & 3, rg = lr & 3;
            if (lane == qo * 16 + n16c) {
                f32x4 a4 = mt ? acc[1][nt] : acc[0][nt];
                float val = (rg == 0) ? a4.x : (rg == 1) ? a4.y : (rg == 2) ? a4.z : a4.w;
                picked[b * NCOL + c] = val;
            }
        }
    }
}

// ---------------- kernel 4: combine partials -> ce -> masked-mean loss -------
__global__ void k4_final(const int* __restrict__ midx, const int* __restrict__ turns,
                         const int* __restrict__ kps,
                         const float* __restrict__ pm, const float* __restrict__ ps,
                         const float* __restrict__ picked, float* __restrict__ out) {
    int tid = threadIdx.x;                 // 384 threads, one per (b,t)
    int i = tid;
    int b = i / Tz, t = i % Tz;
    int e = midx[i];
    float modm  = (e != EMPTYIDX) ? 1.f : 0.f;
    float tmask = (turns[2 * i] >= 0) ? 1.f : 0.f;
    float ce[2];
#pragma unroll
    for (int k = 0; k < 2; ++k) {
        int c = t * 2 + k;
        const float* pmr = pm + ((size_t)b * NCOL + c) * NCH;
        const float* psr = ps + ((size_t)b * NCOL + c) * NCH;
        float m = pmr[0];
        for (int chn = 1; chn < NCH; ++chn) m = fmaxf(m, pmr[chn]);
        float s = 0.f;
        for (int chn = 0; chn < NCH; ++chn) s += psr[chn] * expf(pmr[chn] - m);
        float lse = m + logf(s);
        int tgt = kps[2 * i + k];
        ce[k] = (tgt >= 0) ? (lse - picked[b * NCOL + c]) : 0.f;
    }
    float contrib = 0.5f * (ce[0] + ce[1]) * modm * tmask;

    __shared__ float wsum[6], wmask[6];
    float sl = contrib, sm = tmask;
    for (int o = 32; o > 0; o >>= 1) {
        sl += __shfl_down(sl, o, 64);
        sm += __shfl_down(sm, o, 64);
    }
    int w = tid >> 6, lane = tid & 63;
    if (lane == 0) { wsum[w] = sl; wmask[w] = sm; }
    __syncthreads();
    if (tid == 0) {
        float a = 0.f, mk = 0.f;
        for (int ww = 0; ww < 6; ++ww) { a += wsum[ww]; mk += wmask[ww]; }
        out[0] = a / mk;
    }
}

extern "C" void kernel_launch(void* const* d_in, const int* in_sizes, int n_in,
                              void* d_out, int out_size, void* d_ws, size_t ws_size,
                              hipStream_t stream) {
    const float* seq   = (const float*)d_in[0];  // (32,2048,768)
    const float* W     = (const float*)d_in[1];  // (7,768,768)
    const float* spanw = (const float*)d_in[2];  // (7,768,2)
    const int*   turns = (const int*)d_in[3];    // (32,12,2)
    const int*   kps   = (const int*)d_in[4];    // (32,12,2)
    const int*   midx  = (const int*)d_in[5];    // (32,12)
    float* out = (float*)d_out;

    char* ws = (char*)d_ws;
    float* cW     = (float*)(ws + 0);                  // 384*768 f32   = 1,179,648 B
    float* v      = (float*)(ws + 1179648);            // 32*24*768 f32 = 2,359,296 B
    float* pm     = (float*)(ws + 3538944);            // 32*24*64 f32  =   196,608 B
    float* ps     = (float*)(ws + 3735552);            //               =   196,608 B
    float* picked = (float*)(ws + 3932160);            //                     3,072 B

    hipMemsetAsync(cW, 0, (size_t)384 * Hz * sizeof(float), stream);
    hipLaunchKernelGGL(k1a_cw, dim3(Ez * K1A_ZC * K1A_HC), dim3(256), 0, stream,
                       seq, W, turns, midx, cW);
    hipLaunchKernelGGL(k1b_v, dim3((384 * Hz) / 256), dim3(256), 0, stream,
                       cW, spanw, midx, v);
    hipLaunchKernelGGL(k2_mfma, dim3(Bz * NCH), dim3(64), 0, stream,
                       seq, v, kps, pm, ps, picked);
    hipLaunchKernelGGL(k4_final, dim3(1), dim3(Bz * Tz), 0, stream,
                       midx, turns, kps, pm, ps, picked, out);
}